// Round 1
// baseline (300.712 us; speedup 1.0000x reference)
//
#include <hip/hip_runtime.h>
#include <cstddef>

#define HH 224
#define WW 608
#define HWSZ (HH * WW)

__device__ __forceinline__ float lrelu(float v) { return v > 0.0f ? v : 0.01f * v; }

// CondMul layer, weights gathered from global memory.
// Weight layout: wt[idx][i=0..31][o=0..CO-1], bias bt[idx][o].
// x comes from this thread's LDS column (stride 256 floats).
template <int CO>
__device__ __forceinline__ void cm_global(const float* __restrict__ wt,
                                          const float* __restrict__ bt,
                                          size_t idx,
                                          const float* sxcol,
                                          float (&acc)[CO]) {
    const float* __restrict__ wr = wt + idx * (size_t)(32 * CO);
#pragma unroll
    for (int o = 0; o < CO; o++) acc[o] = 0.0f;
    for (int i = 0; i < 32; i++) {            // rolled: small code, dynamic LDS idx ok
        float xi = sxcol[i * 256];
        const float4* wv = reinterpret_cast<const float4*>(wr + i * CO);
#pragma unroll
        for (int j = 0; j < CO / 4; j++) {
            float4 t = wv[j];
            acc[4 * j + 0] = fmaf(xi, t.x, acc[4 * j + 0]);
            acc[4 * j + 1] = fmaf(xi, t.y, acc[4 * j + 1]);
            acc[4 * j + 2] = fmaf(xi, t.z, acc[4 * j + 2]);
            acc[4 * j + 3] = fmaf(xi, t.w, acc[4 * j + 3]);
        }
    }
    const float* __restrict__ br = bt + idx * CO;
#pragma unroll
    for (int o = 0; o < CO; o++) acc[o] += br[o];
}

// CondMul layer, weights already staged (transposed to [i][o]) in LDS.
template <int CO>
__device__ __forceinline__ void cm_ldsw(const float* sw, const float* sb,
                                        const float* sxcol, float (&acc)[CO]) {
#pragma unroll
    for (int o = 0; o < CO; o++) acc[o] = 0.0f;
    for (int i = 0; i < 32; i++) {
        float xi = sxcol[i * 256];
        const float4* wv = reinterpret_cast<const float4*>(sw + i * CO);
#pragma unroll
        for (int j = 0; j < CO / 4; j++) {
            float4 t = wv[j];
            acc[4 * j + 0] = fmaf(xi, t.x, acc[4 * j + 0]);
            acc[4 * j + 1] = fmaf(xi, t.y, acc[4 * j + 1]);
            acc[4 * j + 2] = fmaf(xi, t.z, acc[4 * j + 2]);
            acc[4 * j + 3] = fmaf(xi, t.w, acc[4 * j + 3]);
        }
    }
#pragma unroll
    for (int o = 0; o < CO; o++) acc[o] += sb[o];
}

template <int CO>
__device__ __forceinline__ void writeback_lrelu(float* sxcol, const float (&acc)[CO]) {
#pragma unroll
    for (int o = 0; o < CO; o++) sxcol[o * 256] = lrelu(acc[o]);
}

template <int CO>
__device__ __forceinline__ int argmax_first(const float (&acc)[CO]) {
    float bv = acc[0];
    int bi = 0;
#pragma unroll
    for (int o = 1; o < CO; o++) {
        if (acc[o] > bv) { bv = acc[o]; bi = o; }
    }
    return bi;
}

extern "C" __global__ __launch_bounds__(256, 3)
void regressor_fused(const float* __restrict__ x_in,
                     const float* __restrict__ w1_0, const float* __restrict__ b1_0,
                     const float* __restrict__ w1_1, const float* __restrict__ b1_1,
                     const float* __restrict__ w1_2, const float* __restrict__ b1_2,
                     const float* __restrict__ w2_0, const float* __restrict__ b2_0,
                     const float* __restrict__ w2_1, const float* __restrict__ b2_1,
                     const float* __restrict__ w2_2, const float* __restrict__ b2_2,
                     const float* __restrict__ w3_0, const float* __restrict__ b3_0,
                     const float* __restrict__ w3_1, const float* __restrict__ b3_1,
                     const float* __restrict__ w3_2, const float* __restrict__ b3_2,
                     const float* __restrict__ wr0, const float* __restrict__ br0,
                     const float* __restrict__ wr1, const float* __restrict__ br1,
                     float* __restrict__ out) {
    const int h = blockIdx.y;
    const int tid = threadIdx.x;
    const int w = blockIdx.x * 256 + tid;

    // Stage-1 per-line weights, transposed to [i][o] so all layers share one shape.
    __shared__ __align__(16) float sW0[32 * 32];
    __shared__ __align__(16) float sW1[32 * 32];
    __shared__ __align__(16) float sW2[32 * 16];
    __shared__ float sB0[32], sB1[32], sB2[16];
    // Per-thread activation columns: sx[i*256 + tid].
    __shared__ float sx[32 * 256];

    for (int t = tid; t < 1024; t += 256) {
        int o = t >> 5, i = t & 31;
        sW0[i * 32 + o] = w1_0[h * 1024 + t];
        sW1[i * 32 + o] = w1_1[h * 1024 + t];
    }
    for (int t = tid; t < 512; t += 256) {
        int o = t >> 5, i = t & 31;
        sW2[i * 16 + o] = w1_2[h * 512 + t];
    }
    if (tid < 32) {
        sB0[tid] = b1_0[h * 32 + tid];
        sB1[tid] = b1_1[h * 32 + tid];
    }
    if (tid < 16) sB2[tid] = b1_2[h * 16 + tid];
    __syncthreads();

    if (w >= WW) return;
    const int base = h * WW + w;
    float* sxcol = sx + tid;

    float acc[32];
    float acc16[16];

    // ---------------- stage 1: per-line MLP, argmax over 16 ----------------
    for (int i = 0; i < 32; i++) sxcol[i * 256] = x_in[i * HWSZ + base];
    cm_ldsw<32>(sW0, sB0, sxcol, acc);
    writeback_lrelu<32>(sxcol, acc);
    cm_ldsw<32>(sW1, sB1, sxcol, acc);
    writeback_lrelu<32>(sxcol, acc);
    cm_ldsw<16>(sW2, sB2, sxcol, acc16);
    const int i1 = argmax_first<16>(acc16);

    // ---------------- stage 2: CondMul chain on (line, class1) ----------------
    for (int i = 0; i < 32; i++) sxcol[i * 256] = x_in[(32 + i) * HWSZ + base];
    const size_t idx2 = (size_t)h * 16 + (size_t)i1;
    cm_global<32>(w2_0, b2_0, idx2, sxcol, acc);
    writeback_lrelu<32>(sxcol, acc);
    cm_global<32>(w2_1, b2_1, idx2, sxcol, acc);
    writeback_lrelu<32>(sxcol, acc);
    cm_global<16>(w2_2, b2_2, idx2, sxcol, acc16);
    const int i2 = argmax_first<16>(acc16);

    const int inds12 = i1 * 12 + (i2 - 2);                   // UNCLIPPED (used below)
    const int c12 = min(max(inds12, 0), 191);                // clipped for table index
    const size_t idx3 = (size_t)h * 192 + (size_t)c12;

    // ---------------- stage 3: CondMul chain on (line, class12) ----------------
    for (int i = 0; i < 32; i++) sxcol[i * 256] = x_in[(64 + i) * HWSZ + base];
    cm_global<32>(w3_0, b3_0, idx3, sxcol, acc);
    writeback_lrelu<32>(sxcol, acc);
    cm_global<32>(w3_1, b3_1, idx3, sxcol, acc);
    writeback_lrelu<32>(sxcol, acc);
    cm_global<16>(w3_2, b3_2, idx3, sxcol, acc16);
    const int i3 = argmax_first<16>(acc16);

    const int inds123 = min(max(inds12 * 10 + (i3 - 3), 0), 1919);

    // ---------------- regressor at predicted leaf ----------------
    for (int i = 0; i < 32; i++) sxcol[i * 256] = x_in[(96 + i) * HWSZ + base];
    const size_t idxs = (size_t)h * 384 + (size_t)(inds123 / 5);
    cm_global<32>(wr0, br0, idxs, sxcol, acc);
    writeback_lrelu<32>(sxcol, acc);

    const size_t idxr = (size_t)h * 1920 + (size_t)inds123;
    const float* __restrict__ wr1r = wr1 + idxr * 32;
    float r = 0.0f;
    for (int i = 0; i < 32; i++) r = fmaf(sxcol[i * 256], wr1r[i], r);
    r += br1[idxr];

    float v = ((float)inds123 + r) / 1920.0f;
    out[base] = (v - 0.1f) / 0.8f;
}

extern "C" void kernel_launch(void* const* d_in, const int* in_sizes, int n_in,
                              void* d_out, int out_size, void* d_ws, size_t ws_size,
                              hipStream_t stream) {
    const float* p[23];
    for (int i = 0; i < 23; i++) p[i] = (const float*)d_in[i];
    dim3 grid(3, HH);
    regressor_fused<<<grid, 256, 0, stream>>>(
        p[0],
        p[1], p[2], p[3], p[4], p[5], p[6],
        p[7], p[8], p[9], p[10], p[11], p[12],
        p[13], p[14], p[15], p[16], p[17], p[18],
        p[19], p[20], p[21], p[22],
        (float*)d_out);
}

// Round 2
// 135.200 us; speedup vs baseline: 2.2242x; 2.2242x over previous
//
#include <hip/hip_runtime.h>
#include <cstddef>

#define HH 224
#define WW 608
#define HWSZ (HH * WW)

__device__ __forceinline__ float lrelu(float v) { return v > 0.0f ? v : 0.01f * v; }

// CondMul with the output dim split across a 4-lane group (lane sub-index s).
// Weight layout [idx][i=0..31][o=0..CO-1] (wmat already offset by idx).
// Activations x[i] live distributed: lane s' of the group holds act[ii] = x[8*s'+ii].
// Each lane computes acc[j] = y[s*CH + j], accumulating i ascending (matches ref).
template <int CO>
__device__ __forceinline__ void cm4(const float* __restrict__ wmat,
                                    const float* __restrict__ bvec,
                                    int s, const float (&act)[8], float (&acc)[CO / 4]) {
    constexpr int CH = CO / 4;
#pragma unroll
    for (int j = 0; j < CH; j++) acc[j] = 0.0f;
#pragma unroll
    for (int sp = 0; sp < 4; sp++) {
#pragma unroll
        for (int ii = 0; ii < 8; ii++) {
            float xi = __shfl(act[ii], sp, 4);          // x[8*sp+ii], broadcast in group
            const float* wr = wmat + (sp * 8 + ii) * CO + s * CH;
            if constexpr (CH == 8) {
                float4 a = *reinterpret_cast<const float4*>(wr);
                float4 b = *reinterpret_cast<const float4*>(wr + 4);
                acc[0] = fmaf(xi, a.x, acc[0]); acc[1] = fmaf(xi, a.y, acc[1]);
                acc[2] = fmaf(xi, a.z, acc[2]); acc[3] = fmaf(xi, a.w, acc[3]);
                acc[4] = fmaf(xi, b.x, acc[4]); acc[5] = fmaf(xi, b.y, acc[5]);
                acc[6] = fmaf(xi, b.z, acc[6]); acc[7] = fmaf(xi, b.w, acc[7]);
            } else {
                float4 a = *reinterpret_cast<const float4*>(wr);
                acc[0] = fmaf(xi, a.x, acc[0]); acc[1] = fmaf(xi, a.y, acc[1]);
                acc[2] = fmaf(xi, a.z, acc[2]); acc[3] = fmaf(xi, a.w, acc[3]);
            }
        }
    }
#pragma unroll
    for (int j = 0; j < CH; j++) acc[j] += bvec[s * CH + j];
}

__device__ __forceinline__ void wb_lrelu8(float (&act)[8], const float (&acc)[8]) {
#pragma unroll
    for (int j = 0; j < 8; j++) act[j] = lrelu(acc[j]);
}

// First-max argmax over 16 values distributed 4-per-lane across the 4-lane group.
__device__ __forceinline__ int argmax4(const float (&v)[4], int s) {
    float bv = v[0];
    int bi = 4 * s;
#pragma unroll
    for (int j = 1; j < 4; j++) {
        if (v[j] > bv) { bv = v[j]; bi = 4 * s + j; }
    }
#pragma unroll
    for (int m = 1; m <= 2; m <<= 1) {
        float ov = __shfl_xor(bv, m, 4);
        int oi = __shfl_xor(bi, m, 4);
        if (ov > bv || (ov == bv && oi < bi)) { bv = ov; bi = oi; }
    }
    return bi;   // all 4 lanes converge to (max value, lowest index)
}

extern "C" __global__ __launch_bounds__(256, 4)
void regressor_fused(const float* __restrict__ x_in,
                     const float* __restrict__ w1_0, const float* __restrict__ b1_0,
                     const float* __restrict__ w1_1, const float* __restrict__ b1_1,
                     const float* __restrict__ w1_2, const float* __restrict__ b1_2,
                     const float* __restrict__ w2_0, const float* __restrict__ b2_0,
                     const float* __restrict__ w2_1, const float* __restrict__ b2_1,
                     const float* __restrict__ w2_2, const float* __restrict__ b2_2,
                     const float* __restrict__ w3_0, const float* __restrict__ b3_0,
                     const float* __restrict__ w3_1, const float* __restrict__ b3_1,
                     const float* __restrict__ w3_2, const float* __restrict__ b3_2,
                     const float* __restrict__ wr0, const float* __restrict__ br0,
                     const float* __restrict__ wr1, const float* __restrict__ br1,
                     float* __restrict__ out) {
    const int h = blockIdx.y;
    const int tid = threadIdx.x;
    const int p = tid >> 2;          // pixel within block (0..63)
    const int s = tid & 3;           // output-chunk sub-lane (0..3)
    const int w = blockIdx.x * 64 + p;
    const bool valid = (w < WW);
    const int wc = valid ? w : (WW - 1);   // clamped: tail lanes compute a duplicate
    const int base = h * WW + wc;

    // ---- stage-1 per-line weights, staged transposed to [i][o] (linear LDS writes,
    //      transposed global reads: matrix is 4KB -> L2 resident, conflict-free LDS) ----
    __shared__ __align__(16) float sW0[1024];
    __shared__ __align__(16) float sW1[1024];
    __shared__ __align__(16) float sW2[512];
    for (int t = tid; t < 1024; t += 256) {
        int i = t >> 5, o = t & 31;
        sW0[t] = w1_0[h * 1024 + o * 32 + i];
        sW1[t] = w1_1[h * 1024 + o * 32 + i];
    }
    for (int t = tid; t < 512; t += 256) {
        int i = t >> 4, o = t & 15;
        sW2[t] = w1_2[h * 512 + o * 32 + i];
    }
    __syncthreads();

    float act[8], acc8[8], acc4[4];

    // ---------------- stage 1: per-line MLP -> class1 ----------------
#pragma unroll
    for (int ii = 0; ii < 8; ii++) act[ii] = x_in[(8 * s + ii) * HWSZ + base];
    cm4<32>(sW0, b1_0 + h * 32, s, act, acc8);
    wb_lrelu8(act, acc8);
    cm4<32>(sW1, b1_1 + h * 32, s, act, acc8);
    wb_lrelu8(act, acc8);
    cm4<16>(sW2, b1_2 + h * 16, s, act, acc4);
    const int i1 = argmax4(acc4, s);

    // ---------------- stage 2: CondMul on (line, class1) ----------------
#pragma unroll
    for (int ii = 0; ii < 8; ii++) act[ii] = x_in[(32 + 8 * s + ii) * HWSZ + base];
    const size_t idx2 = (size_t)h * 16 + (size_t)i1;
    cm4<32>(w2_0 + idx2 * 1024, b2_0 + idx2 * 32, s, act, acc8);
    wb_lrelu8(act, acc8);
    cm4<32>(w2_1 + idx2 * 1024, b2_1 + idx2 * 32, s, act, acc8);
    wb_lrelu8(act, acc8);
    cm4<16>(w2_2 + idx2 * 512, b2_2 + idx2 * 16, s, act, acc4);
    const int i2 = argmax4(acc4, s);

    const int inds12 = i1 * 12 + (i2 - 2);               // unclipped (used below)
    const int c12 = min(max(inds12, 0), 191);
    const size_t idx3 = (size_t)h * 192 + (size_t)c12;

    // ---------------- stage 3: CondMul on (line, class12) ----------------
#pragma unroll
    for (int ii = 0; ii < 8; ii++) act[ii] = x_in[(64 + 8 * s + ii) * HWSZ + base];
    cm4<32>(w3_0 + idx3 * 1024, b3_0 + idx3 * 32, s, act, acc8);
    wb_lrelu8(act, acc8);
    cm4<32>(w3_1 + idx3 * 1024, b3_1 + idx3 * 32, s, act, acc8);
    wb_lrelu8(act, acc8);
    cm4<16>(w3_2 + idx3 * 512, b3_2 + idx3 * 16, s, act, acc4);
    const int i3 = argmax4(acc4, s);

    const int inds123 = min(max(inds12 * 10 + (i3 - 3), 0), 1919);

    // ---------------- regressor at predicted leaf ----------------
#pragma unroll
    for (int ii = 0; ii < 8; ii++) act[ii] = x_in[(96 + 8 * s + ii) * HWSZ + base];
    const size_t idxs = (size_t)h * 384 + (size_t)(inds123 / 5);
    cm4<32>(wr0 + idxs * 1024, br0 + idxs * 32, s, act, acc8);
    wb_lrelu8(act, acc8);

    const size_t idxr = (size_t)h * 1920 + (size_t)inds123;
    const float* __restrict__ wr1r = wr1 + idxr * 32 + 8 * s;
    float4 wa = *reinterpret_cast<const float4*>(wr1r);
    float4 wb = *reinterpret_cast<const float4*>(wr1r + 4);
    float rpart = 0.0f;
    rpart = fmaf(act[0], wa.x, rpart); rpart = fmaf(act[1], wa.y, rpart);
    rpart = fmaf(act[2], wa.z, rpart); rpart = fmaf(act[3], wa.w, rpart);
    rpart = fmaf(act[4], wb.x, rpart); rpart = fmaf(act[5], wb.y, rpart);
    rpart = fmaf(act[6], wb.z, rpart); rpart = fmaf(act[7], wb.w, rpart);
    rpart += __shfl_xor(rpart, 1, 4);
    rpart += __shfl_xor(rpart, 2, 4);
    const float r = rpart + br1[idxr];

    if (s == 0 && valid) {
        float v = ((float)inds123 + r) * (1.0f / 1920.0f);
        out[h * WW + w] = (v - 0.1f) * 1.25f;
    }
}

extern "C" void kernel_launch(void* const* d_in, const int* in_sizes, int n_in,
                              void* d_out, int out_size, void* d_ws, size_t ws_size,
                              hipStream_t stream) {
    const float* p[23];
    for (int i = 0; i < 23; i++) p[i] = (const float*)d_in[i];
    dim3 grid(10, HH);   // 64 pixels per block, 4 lanes per pixel
    regressor_fused<<<grid, 256, 0, stream>>>(
        p[0],
        p[1], p[2], p[3], p[4], p[5], p[6],
        p[7], p[8], p[9], p[10], p[11], p[12],
        p[13], p[14], p[15], p[16], p[17], p[18],
        p[19], p[20], p[21], p[22],
        (float*)d_out);
}